// Round 7
// baseline (899.847 us; speedup 1.0000x reference)
//
#include <hip/hip_runtime.h>

#define BATCH 8
#define T 4096
#define NCH 256
#define NCTX 80
#define NLAYERS 8

typedef unsigned short u16;
typedef __attribute__((ext_vector_type(8))) short short8;
typedef __attribute__((ext_vector_type(4))) short short4v;
typedef __attribute__((ext_vector_type(4))) float float4v;

__device__ __forceinline__ float b2f(u16 u) {
    unsigned v = ((unsigned)u) << 16;
    float f;
    __builtin_memcpy(&f, &v, 4);
    return f;
}
__device__ __forceinline__ u16 f2b(float f) {
    unsigned v;
    __builtin_memcpy(&v, &f, 4);
    unsigned r = v + 0x7FFFu + ((v >> 16) & 1u);
    return (u16)(r >> 16);
}

typedef const __attribute__((address_space(1))) unsigned int* gp1;
typedef __attribute__((address_space(3))) unsigned int* lp3;
// async global->LDS, 16B per lane; LDS dest = wave-uniform base + lane*16
__device__ __forceinline__ void gl_lds16(const u16* g, u16* l) {
    __builtin_amdgcn_global_load_lds((gp1)g, (lp3)l, 16, 0, 0);
}

template <bool F32>
__device__ __forceinline__ float LD(const void* p, size_t i) {
    if constexpr (F32) return ((const float*)p)[i];
    else return b2f(((const u16*)p)[i]);
}
template <bool F32>
__device__ __forceinline__ bool skipv(const int* flag) {
    int f = *flag;
    return F32 ? (f != 0) : (f == 0);
}

// ---------------- dtype probe ----------------
__global__ void probe_kernel(const u16* __restrict__ fc, int* __restrict__ flag) {
    __shared__ int cnt;
    if (threadIdx.x == 0) cnt = 0;
    __syncthreads();
    int local = 0;
#pragma unroll
    for (int j = 0; j < 16; j++) {
        u16 u = fc[2 * (threadIdx.x * 16 + j)];
        int e = (u >> 7) & 0xFF;
        if (e >= 0x50 && e <= 0x85) local++;
    }
    atomicAdd(&cnt, local);
    __syncthreads();
    if (threadIdx.x == 0) *flag = (cnt >= 2048) ? 1 : 0;  // 1 = bf16 inputs
}

// ---------------- generic convert to bf16 ----------------
template <bool F32>
__global__ void cvt_kernel(const void* __restrict__ src, u16* __restrict__ dst, int n,
                           const int* __restrict__ flag) {
    if (skipv<F32>(flag)) return;
    int i = blockIdx.x * 256 + threadIdx.x;
    if (i < n) dst[i] = f2b(LD<F32>(src, i));
}

// ---------------- build Wc [8][512][864] ----------------
template <bool F32>
__global__ void prep_wc(const void* __restrict__ in_w, const void* __restrict__ in_b,
                        const void* __restrict__ cond_w, const void* __restrict__ cond_b,
                        u16* __restrict__ Wc, const int* __restrict__ flag) {
    if (skipv<F32>(flag)) return;
    int row = blockIdx.x;  // 0..4095 = l*512+o
    for (int it = 0; it < 4; it++) {
        int col = it * 256 + threadIdx.x;
        if (col >= 864) break;
        float v;
        if (col < 256)       v = LD<F32>(in_w, ((size_t)row * 256 + col) * 3);
        else if (col < 512)  v = LD<F32>(in_w, ((size_t)row * 256 + (col - 256)) * 3 + 1);
        else if (col < 768)  v = LD<F32>(in_w, ((size_t)row * 256 + (col - 512)) * 3 + 2);
        else if (col < 848)  v = LD<F32>(cond_w, (size_t)row * 80 + (col - 768));
        else if (col == 848) v = LD<F32>(in_b, row) + LD<F32>(cond_b, row);
        else                 v = 0.f;
        Wc[(size_t)row * 864 + col] = f2b(v);
    }
}

// ---------------- transpose context -> ctx_t [B][T][96] ----------------
template <bool F32>
__global__ void prep_ctx(const void* __restrict__ ctx, u16* __restrict__ ctxt,
                         const int* __restrict__ flag) {
    if (skipv<F32>(flag)) return;
    __shared__ float sm[80][65];
    const int tid = threadIdx.x;
    const int b = blockIdx.y, t0 = blockIdx.x * 64;
    for (int it = 0; it < 20; it++) {
        int e = it * 256 + tid;
        int j = e >> 6, tt = e & 63;
        sm[j][tt] = LD<F32>(ctx, ((size_t)b * 80 + j) * T + t0 + tt);
    }
    __syncthreads();
    for (int it = 0; it < 24; it++) {
        int e = it * 256 + tid;
        int r = e / 96, c = e - r * 96;
        float v = (c < 80) ? sm[c][r] : (c == 80 ? 1.f : 0.f);
        ctxt[((size_t)b * T + t0 + r) * 96 + c] = f2b(v);
    }
}

// ---------------- start conv (4 -> 256, 1x1) -> x_t [B][T][256] ----------------
template <bool F32>
__global__ void start_kernel(const void* __restrict__ fc, const void* __restrict__ w,
                             const void* __restrict__ bias, u16* __restrict__ xt,
                             const int* __restrict__ flag) {
    if (skipv<F32>(flag)) return;
    __shared__ float fsm[4][64];
    __shared__ float wsm[1024];
    __shared__ float bsm[256];
    const int tid = threadIdx.x;
    const int b = blockIdx.y, t0 = blockIdx.x * 64;
    fsm[tid >> 6][tid & 63] = LD<F32>(fc, ((size_t)b * 8 + (tid >> 6)) * T + t0 + (tid & 63));
    for (int it = 0; it < 4; it++) wsm[it * 256 + tid] = LD<F32>(w, it * 256 + tid);
    bsm[tid] = LD<F32>(bias, tid);
    __syncthreads();
    for (int r = 0; r < 64; r++) {
        int c = tid;
        float a = bsm[c];
#pragma unroll
        for (int k = 0; k < 4; k++) a += wsm[c * 4 + k] * fsm[k][r];
        xt[((size_t)b * T + t0 + r) * 256 + c] = f2b(a);
    }
}

// ---------------- fused WaveNet layer (global_load_lds staging, <=64KiB LDS) ----------------
// grid (T/64, B), block 256 (4 waves). LDS (u16 idx), 25088 u16 = 50,176 B:
//   phase1: A [0,2048) stride 32 | B [2048,18432) stride 32
//   phase2/3: acts [0,16896) stride 264 (overlaps dead A/B) | Bs2 [16896,25088) stride 32
// XOR chunk swizzle (chunk ^= row&3) on stride-32 tiles: b128 reads -> 2-way (free).
#define LA 0
#define LB 2048
#define LACT 0
#define LB2 16896
__global__ __launch_bounds__(256, 2) void layer_fused(
    const u16* __restrict__ xin, u16* __restrict__ xout, const u16* __restrict__ Wc,
    const u16* __restrict__ Wrs, const u16* __restrict__ rsb, const u16* __restrict__ ctxt,
    u16* __restrict__ oacc, int layer, int dil, int first, int last) {
    __shared__ u16 lds[25088];
    const int tid = threadIdx.x;
    const int w = tid >> 6, lane = tid & 63, l15 = lane & 15, quad = lane >> 4;
    const int b = blockIdx.y;
    const int t0 = blockIdx.x * 64;
    const int srow = tid >> 2;                         // 0..63
    const int skz = (((tid & 3) ^ (srow & 3)) * 8);    // swizzled source chunk (u16)
    const int rq = (quad ^ (l15 & 3)) * 8;             // swizzled reader chunk (u16)
    const int wbase = w * 512;                         // wave-uniform LDS dest base (u16)

    const u16* xb = xin + (size_t)b * T * 256;
    const u16* cb = ctxt + (size_t)b * T * 96;
    const u16* Wl = Wc + (size_t)layer * 512 * 864;

    float4v acc[4][8];
#pragma unroll
    for (int m = 0; m < 4; m++)
#pragma unroll
        for (int j = 0; j < 8; j++) acc[m][j] = (float4v){0.f, 0.f, 0.f, 0.f};

    // ---- phase 1: a[t][out] = im2col(x; ctx; 1.0) . Wc  (K=864, 27 steps of 32) ----
    const u16* wrow = Wl + (size_t)srow * 864 + skz;
    for (int s = 0; s < 27; s++) {
        // stage A (64 x 32)
        if (s < 24) {
            int seg = s >> 3, cs = s & 7;
            int t = t0 + srow + (seg - 1) * dil;
            const u16* asrc = xb + (size_t)t * 256 + cs * 32 + skz;
            bool fast = (seg == 1) || (seg == 0 ? (t0 >= dil) : (t0 + 64 + dil <= T));
            if (fast) {
                gl_lds16(asrc, &lds[LA + wbase]);
            } else {
                short8 av = (t >= 0 && t < T) ? *(const short8*)asrc
                                              : (short8){0, 0, 0, 0, 0, 0, 0, 0};
                *(short4v*)&lds[LA + tid * 8] = __builtin_shufflevector(av, av, 0, 1, 2, 3);
                *(short4v*)&lds[LA + tid * 8 + 4] = __builtin_shufflevector(av, av, 4, 5, 6, 7);
            }
        } else {
            gl_lds16(cb + (size_t)(t0 + srow) * 96 + (s - 24) * 32 + skz, &lds[LA + wbase]);
        }
        // stage B (512 x 32)
#pragma unroll
        for (int r = 0; r < 8; r++)
            gl_lds16(wrow + (size_t)r * 64 * 864 + s * 32, &lds[LB + r * 2048 + wbase]);
        __syncthreads();
        // compute
        short8 af[4], bf[8];
#pragma unroll
        for (int m = 0; m < 4; m++)
            af[m] = *(const short8*)&lds[LA + (m * 16 + l15) * 32 + rq];
#pragma unroll
        for (int j = 0; j < 8; j++) {
            int nt = (j < 4) ? (4 * w + j) : (16 + 4 * w + (j - 4));
            bf[j] = *(const short8*)&lds[LB + (nt * 16 + l15) * 32 + rq];
        }
#pragma unroll
        for (int m = 0; m < 4; m++)
#pragma unroll
            for (int j = 0; j < 8; j++)
                acc[m][j] = __builtin_amdgcn_mfma_f32_16x16x32_bf16(af[m], bf[j], acc[m][j], 0, 0, 0);
        __syncthreads();
    }

    // ---- phase 2: gated activation -> acts in LDS (overlaps dead A/B region) ----
#pragma unroll
    for (int m = 0; m < 4; m++) {
#pragma unroll
        for (int j = 0; j < 4; j++) {
            int c = 64 * w + 16 * j + l15;
#pragma unroll
            for (int r = 0; r < 4; r++) {
                int tl = m * 16 + quad * 4 + r;
                float at = acc[m][j][r], as = acc[m][j + 4][r];
                float e2 = __expf(2.f * at);
                float th = 1.f - 2.f / (e2 + 1.f);
                float sg = 1.f / (1.f + __expf(-as));
                lds[LACT + tl * 264 + c] = f2b(th * sg);
            }
        }
    }
    // (ordering: phase-3 step-0's barrier separates acts writes from reads)

    // ---- phase 3: rs = acts . Wrs^T (K=256, 8 steps of 32), two out-halves ----
    u16* xo = xout + (size_t)b * T * 256;
    u16* oo = oacc + (size_t)b * T * 256;
    const int nhalf = last ? 1 : 2;
#pragma unroll 1
    for (int half = 0; half < nhalf; half++) {
        float4v acc2[4][4];
#pragma unroll
        for (int m = 0; m < 4; m++)
#pragma unroll
            for (int j = 0; j < 4; j++) acc2[m][j] = (float4v){0.f, 0.f, 0.f, 0.f};
        const u16* w2 = Wrs + ((size_t)(layer * 512 + half * 256 + srow)) * 256 + skz;
        for (int s = 0; s < 8; s++) {
#pragma unroll
            for (int r = 0; r < 4; r++)
                gl_lds16(w2 + (size_t)(r * 64) * 256 + s * 32, &lds[LB2 + r * 2048 + wbase]);
            __syncthreads();
            short8 af2[4], bf2[4];
#pragma unroll
            for (int m = 0; m < 4; m++)
                af2[m] = *(const short8*)&lds[LACT + (m * 16 + l15) * 264 + s * 32 + quad * 8];
#pragma unroll
            for (int j = 0; j < 4; j++)
                bf2[j] = *(const short8*)&lds[LB2 + ((4 * w + j) * 16 + l15) * 32 + rq];
#pragma unroll
            for (int m = 0; m < 4; m++)
#pragma unroll
                for (int j = 0; j < 4; j++)
                    acc2[m][j] =
                        __builtin_amdgcn_mfma_f32_16x16x32_bf16(af2[m], bf2[j], acc2[m][j], 0, 0, 0);
            __syncthreads();
        }
        // epilogue: scattered global RMW from fragments
        float bias[4];
#pragma unroll
        for (int j = 0; j < 4; j++)
            bias[j] = b2f(rsb[layer * 512 + half * 256 + 64 * w + 16 * j + l15]);
#pragma unroll
        for (int m = 0; m < 4; m++) {
#pragma unroll
            for (int j = 0; j < 4; j++) {
                int c = 64 * w + 16 * j + l15;
#pragma unroll
                for (int r = 0; r < 4; r++) {
                    int t = t0 + m * 16 + quad * 4 + r;
                    size_t idx = (size_t)t * 256 + c;
                    float v = acc2[m][j][r] + bias[j];
                    if (half == 0) {
                        if (last) oo[idx] = f2b(b2f(oo[idx]) + v);   // skip += rs[:256] (last)
                        else      xo[idx] = f2b(b2f(xb[idx]) + v);  // x_new = x_old + rs[:256]
                    } else {
                        oo[idx] = first ? f2b(v) : f2b(b2f(oo[idx]) + v);  // skip accumulate
                    }
                }
            }
        }
    }
}

// ---------------- end conv (256 -> 8) + affine + output assembly ----------------
template <bool F32>
__global__ void end_kernel(const u16* __restrict__ oacc, const void* __restrict__ w_end,
                           const void* __restrict__ b_end, const void* __restrict__ fc,
                           void* __restrict__ out, const int* __restrict__ flag) {
    if (skipv<F32>(flag)) return;
    __shared__ float wsm[2048];
    __shared__ float bsm[8];
    const int tid = threadIdx.x;
    for (int it = 0; it < 8; it++) wsm[it * 256 + tid] = LD<F32>(w_end, it * 256 + tid);
    if (tid < 8) bsm[tid] = LD<F32>(b_end, tid);
    __syncthreads();
    int gid = blockIdx.x * 256 + tid;  // 0..32767
    int b = gid >> 12, t = gid & 4095;
    float o8[8];
#pragma unroll
    for (int o = 0; o < 8; o++) o8[o] = bsm[o];
    const u16* orow = oacc + (size_t)(b * T + t) * 256;
    for (int c8 = 0; c8 < 32; c8++) {
        short8 v8 = *(const short8*)(orow + c8 * 8);
#pragma unroll
        for (int k = 0; k < 8; k++) {
            float v = b2f((u16)v8[k]);
            int c = c8 * 8 + k;
#pragma unroll
            for (int o = 0; o < 8; o++) o8[o] += wsm[o * 256 + c] * v;
        }
    }
    size_t ob8 = (size_t)b * 8 * T;
#pragma unroll
    for (int j = 0; j < 4; j++) {
        float f1v = LD<F32>(fc, ob8 + (size_t)(4 + j) * T + t);
        float ls = o8[4 + j];
        float val = __expf(ls) * f1v + o8[j];
        if constexpr (F32) {
            float* o = (float*)out;
            o[ob8 + (size_t)j * T + t] = ((const float*)fc)[ob8 + (size_t)j * T + t];
            o[ob8 + (size_t)(4 + j) * T + t] = val;
            o[(size_t)BATCH * 8 * T + ((size_t)b * 4 + j) * T + t] = ls;
        } else {
            u16* o = (u16*)out;
            o[ob8 + (size_t)j * T + t] = ((const u16*)fc)[ob8 + (size_t)j * T + t];
            o[ob8 + (size_t)(4 + j) * T + t] = f2b(val);
            o[(size_t)BATCH * 8 * T + ((size_t)b * 4 + j) * T + t] = f2b(ls);
        }
    }
}

template <bool F32>
static void launch_prep(const void* forecast, const void* context, const void* start_w,
                        const void* start_b, const void* cond_w, const void* cond_b,
                        const void* in_w, const void* in_b, const void* rs_w, const void* rs_b,
                        u16* xA, u16* ctxt, u16* Wc, u16* Wrs, u16* rsb, const int* flag,
                        hipStream_t stream) {
    cvt_kernel<F32><<<4096, 256, 0, stream>>>(rs_w, Wrs, 8 * 512 * 256, flag);
    cvt_kernel<F32><<<16, 256, 0, stream>>>(rs_b, rsb, 4096, flag);
    prep_wc<F32><<<4096, 256, 0, stream>>>(in_w, in_b, cond_w, cond_b, Wc, flag);
    prep_ctx<F32><<<dim3(64, BATCH), 256, 0, stream>>>(context, ctxt, flag);
    start_kernel<F32><<<dim3(64, BATCH), 256, 0, stream>>>(forecast, start_w, start_b, xA, flag);
}

extern "C" void kernel_launch(void* const* d_in, const int* in_sizes, int n_in,
                              void* d_out, int out_size, void* d_ws, size_t ws_size,
                              hipStream_t stream) {
    const void* forecast = d_in[0];
    const void* context  = d_in[1];
    const void* start_w  = d_in[2];
    const void* start_b  = d_in[3];
    const void* cond_w   = d_in[4];
    const void* cond_b   = d_in[5];
    const void* in_w     = d_in[6];
    const void* in_b     = d_in[7];
    const void* rs_w     = d_in[8];
    const void* rs_b     = d_in[9];
    const void* end_w    = d_in[10];
    const void* end_b    = d_in[11];

    char* W = (char*)d_ws;
    int* flag = (int*)(W + 0);
    u16* xA   = (u16*)(W + 256);                  // 16,777,216
    u16* xB   = (u16*)(W + 256 + 16777216);       // 16,777,216
    u16* oacc = (u16*)(W + 256 + 33554432);       // 16,777,216
    u16* ctxt = (u16*)(W + 256 + 50331648);       //  6,291,456
    u16* Wc   = (u16*)(W + 256 + 56623104);       //  7,077,888
    u16* Wrs  = (u16*)(W + 256 + 63700992);       //  2,097,152
    u16* rsb  = (u16*)(W + 256 + 65798144);       //      8,192  -> total ~62.8 MiB

    probe_kernel<<<1, 256, 0, stream>>>((const u16*)forecast, flag);

    launch_prep<false>(forecast, context, start_w, start_b, cond_w, cond_b, in_w, in_b, rs_w,
                       rs_b, xA, ctxt, Wc, Wrs, rsb, flag, stream);
    launch_prep<true>(forecast, context, start_w, start_b, cond_w, cond_b, in_w, in_b, rs_w,
                      rs_b, xA, ctxt, Wc, Wrs, rsb, flag, stream);

    const int dil[NLAYERS] = {1, 2, 4, 8, 16, 32, 64, 128};
    for (int l = 0; l < NLAYERS; l++) {
        const u16* xi = (l & 1) ? xB : xA;
        u16* xo = (l & 1) ? xA : xB;
        layer_fused<<<dim3(64, BATCH), 256, 0, stream>>>(xi, xo, Wc, Wrs, rsb, ctxt, oacc, l,
                                                         dil[l], l == 0, l == NLAYERS - 1);
    }

    end_kernel<false><<<128, 256, 0, stream>>>(oacc, end_w, end_b, forecast, d_out, flag);
    end_kernel<true><<<128, 256, 0, stream>>>(oacc, end_w, end_b, forecast, d_out, flag);
}

// Round 9
// 840.386 us; speedup vs baseline: 1.0708x; 1.0708x over previous
//
#include <hip/hip_runtime.h>

#define BATCH 8
#define T 4096
#define NCH 256
#define NCTX 80
#define NLAYERS 8

typedef unsigned short u16;
typedef __attribute__((ext_vector_type(8))) short short8;
typedef __attribute__((ext_vector_type(4))) short short4v;
typedef __attribute__((ext_vector_type(4))) float float4v;

__device__ __forceinline__ float b2f(u16 u) {
    unsigned v = ((unsigned)u) << 16;
    float f;
    __builtin_memcpy(&f, &v, 4);
    return f;
}
__device__ __forceinline__ u16 f2b(float f) {
    unsigned v;
    __builtin_memcpy(&v, &f, 4);
    unsigned r = v + 0x7FFFu + ((v >> 16) & 1u);
    return (u16)(r >> 16);
}

typedef const __attribute__((address_space(1))) unsigned int* gp1;
typedef __attribute__((address_space(3))) unsigned int* lp3;
__device__ __forceinline__ void gl_lds16(const u16* g, u16* l) {
    __builtin_amdgcn_global_load_lds((gp1)g, (lp3)l, 16, 0, 0);
}

template <bool F32>
__device__ __forceinline__ float LD(const void* p, size_t i) {
    if constexpr (F32) return ((const float*)p)[i];
    else return b2f(((const u16*)p)[i]);
}
template <bool F32>
__device__ __forceinline__ bool skipv(const int* flag) {
    int f = *flag;
    return F32 ? (f != 0) : (f == 0);
}

// ---------------- dtype probe ----------------
__global__ void probe_kernel(const u16* __restrict__ fc, int* __restrict__ flag) {
    __shared__ int cnt;
    if (threadIdx.x == 0) cnt = 0;
    __syncthreads();
    int local = 0;
#pragma unroll
    for (int j = 0; j < 16; j++) {
        u16 u = fc[2 * (threadIdx.x * 16 + j)];
        int e = (u >> 7) & 0xFF;
        if (e >= 0x50 && e <= 0x85) local++;
    }
    atomicAdd(&cnt, local);
    __syncthreads();
    if (threadIdx.x == 0) *flag = (cnt >= 2048) ? 1 : 0;  // 1 = bf16 inputs
}

// ---------------- generic convert to bf16 ----------------
template <bool F32>
__global__ void cvt_kernel(const void* __restrict__ src, u16* __restrict__ dst, int n,
                           const int* __restrict__ flag) {
    if (skipv<F32>(flag)) return;
    int i = blockIdx.x * 256 + threadIdx.x;
    if (i < n) dst[i] = f2b(LD<F32>(src, i));
}

// ---------------- build Wc [8][512][864] ----------------
template <bool F32>
__global__ void prep_wc(const void* __restrict__ in_w, const void* __restrict__ in_b,
                        const void* __restrict__ cond_w, const void* __restrict__ cond_b,
                        u16* __restrict__ Wc, const int* __restrict__ flag) {
    if (skipv<F32>(flag)) return;
    int row = blockIdx.x;  // 0..4095 = l*512+o
    for (int it = 0; it < 4; it++) {
        int col = it * 256 + threadIdx.x;
        if (col >= 864) break;
        float v;
        if (col < 256)       v = LD<F32>(in_w, ((size_t)row * 256 + col) * 3);
        else if (col < 512)  v = LD<F32>(in_w, ((size_t)row * 256 + (col - 256)) * 3 + 1);
        else if (col < 768)  v = LD<F32>(in_w, ((size_t)row * 256 + (col - 512)) * 3 + 2);
        else if (col < 848)  v = LD<F32>(cond_w, (size_t)row * 80 + (col - 768));
        else if (col == 848) v = LD<F32>(in_b, row) + LD<F32>(cond_b, row);
        else                 v = 0.f;
        Wc[(size_t)row * 864 + col] = f2b(v);
    }
}

// ---------------- transpose context -> ctx_t [B][T][96] ----------------
template <bool F32>
__global__ void prep_ctx(const void* __restrict__ ctx, u16* __restrict__ ctxt,
                         const int* __restrict__ flag) {
    if (skipv<F32>(flag)) return;
    __shared__ float sm[80][65];
    const int tid = threadIdx.x;
    const int b = blockIdx.y, t0 = blockIdx.x * 64;
    for (int it = 0; it < 20; it++) {
        int e = it * 256 + tid;
        int j = e >> 6, tt = e & 63;
        sm[j][tt] = LD<F32>(ctx, ((size_t)b * 80 + j) * T + t0 + tt);
    }
    __syncthreads();
    for (int it = 0; it < 24; it++) {
        int e = it * 256 + tid;
        int r = e / 96, c = e - r * 96;
        float v = (c < 80) ? sm[c][r] : (c == 80 ? 1.f : 0.f);
        ctxt[((size_t)b * T + t0 + r) * 96 + c] = f2b(v);
    }
}

// ---------------- start conv (4 -> 256, 1x1) -> x_t [B][T][256] ----------------
template <bool F32>
__global__ void start_kernel(const void* __restrict__ fc, const void* __restrict__ w,
                             const void* __restrict__ bias, u16* __restrict__ xt,
                             const int* __restrict__ flag) {
    if (skipv<F32>(flag)) return;
    __shared__ float fsm[4][64];
    __shared__ float wsm[1024];
    __shared__ float bsm[256];
    const int tid = threadIdx.x;
    const int b = blockIdx.y, t0 = blockIdx.x * 64;
    fsm[tid >> 6][tid & 63] = LD<F32>(fc, ((size_t)b * 8 + (tid >> 6)) * T + t0 + (tid & 63));
    for (int it = 0; it < 4; it++) wsm[it * 256 + tid] = LD<F32>(w, it * 256 + tid);
    bsm[tid] = LD<F32>(bias, tid);
    __syncthreads();
    for (int r = 0; r < 64; r++) {
        int c = tid;
        float a = bsm[c];
#pragma unroll
        for (int k = 0; k < 4; k++) a += wsm[c * 4 + k] * fsm[k][r];
        xt[((size_t)b * T + t0 + r) * 256 + c] = f2b(a);
    }
}

// ================= layer conv kernel: dilated conv+cond GEMM + gate -> acts =================
// grid (T/128=32, B=8), 512 threads (8 waves). M=128t, N=512out, K=864.
// Chunks: 27 K-steps x 2 out-halves = 54. B dbuf 2x16KB, A triple-buf 3x8KB.
// One barrier per chunk: stage(c+1) DMA issued before compute(c); barrier drains it.
// LDS u16 layout: A bufs [0,12288) (3x4096), B bufs [12288,28672) (2x8192). 57,344 B.
__global__ __launch_bounds__(512, 1) void layer_conv(
    const u16* __restrict__ x, const u16* __restrict__ Wc, const u16* __restrict__ ctxt,
    u16* __restrict__ acts, int layer, int dil) {
    __shared__ u16 lds[28672];
    const int tid = threadIdx.x;
    const int w = tid >> 6, lane = tid & 63;
    const int l15 = lane & 15, quad = lane >> 4;
    const int iw = w >> 1, jc = w & 1;   // wave tile: t-rows 32*iw, out-cols 128*jc (per half)
    const int b = blockIdx.y, t0 = blockIdx.x * 128;
    const int lrow = lane >> 2;                       // 0..15
    const int lsw = ((lane & 3) ^ (lrow & 3)) * 8;    // swizzled src chunk (u16)
    const int rq = (quad ^ (l15 & 3)) * 8;            // swizzled reader chunk (u16)

    const u16* xb = x + (size_t)b * T * 256;
    const u16* cb = ctxt + (size_t)b * T * 96;
    const u16* Wl = Wc + (size_t)layer * 512 * 864;

    float4v acc0[2][8], acc1[2][8];  // [m][jj]: acc0 = tanh half, acc1 = sigm half
#pragma unroll
    for (int m = 0; m < 2; m++)
#pragma unroll
        for (int jj = 0; jj < 8; jj++) {
            acc0[m][jj] = (float4v){0.f, 0.f, 0.f, 0.f};
            acc1[m][jj] = (float4v){0.f, 0.f, 0.f, 0.f};
        }

    auto stageA = [&](int s, int abuf) {  // 128 rows x 32 u16; wave w stages rows 16w..16w+16
        u16* dst = &lds[abuf * 4096 + w * 512];
        if (s < 24) {
            int seg = s >> 3, cs = s & 7;
            int tb = t0 + 16 * w + (seg - 1) * dil;
            if (tb >= 0 && tb + 16 <= T) {
                gl_lds16(xb + (size_t)(tb + lrow) * 256 + cs * 32 + lsw, dst);
            } else {  // boundary tile: manual masked path (rare)
                int t = tb + lrow;
                short8 av = (short8){0, 0, 0, 0, 0, 0, 0, 0};
                if (t >= 0 && t < T)
                    av = *(const short8*)(xb + (size_t)t * 256 + cs * 32 + lsw);
                *(short4v*)&dst[lane * 8] = __builtin_shufflevector(av, av, 0, 1, 2, 3);
                *(short4v*)&dst[lane * 8 + 4] = __builtin_shufflevector(av, av, 4, 5, 6, 7);
            }
        } else {
            gl_lds16(cb + (size_t)(t0 + 16 * w + lrow) * 96 + (s - 24) * 32 + lsw, dst);
        }
    };
    auto stageB = [&](int c) {  // 256 rows (out-half) x 32 u16; wave w: rows 32w..32w+32
        int s = c >> 1;
        const u16* src = Wl + (size_t)((c & 1) * 256 + 32 * w + lrow) * 864 + s * 32 + lsw;
        u16* dst = &lds[12288 + (c & 1) * 8192 + w * 1024];
        gl_lds16(src, dst);
        gl_lds16(src + (size_t)16 * 864, dst + 512);
    };

    stageA(0, 0);
    stageA(1, 1);
    stageB(0);
    __syncthreads();
#pragma unroll 1
    for (int c = 0; c < 54; c++) {
        int s = c >> 1;
        if ((c & 1) == 0 && s + 2 < 27) stageA(s + 2, (s + 2) % 3);
        if (c + 1 < 54) stageB(c + 1);
        const u16* bA = &lds[(s % 3) * 4096];
        const u16* bB = &lds[12288 + (c & 1) * 8192];
        short8 af0 = *(const short8*)&bA[(32 * iw + l15) * 32 + rq];
        short8 af1 = *(const short8*)&bA[(32 * iw + 16 + l15) * 32 + rq];
        if ((c & 1) == 0) {
#pragma unroll
            for (int jj = 0; jj < 8; jj++) {
                short8 bf = *(const short8*)&bB[(128 * jc + 16 * jj + l15) * 32 + rq];
                acc0[0][jj] = __builtin_amdgcn_mfma_f32_16x16x32_bf16(af0, bf, acc0[0][jj], 0, 0, 0);
                acc0[1][jj] = __builtin_amdgcn_mfma_f32_16x16x32_bf16(af1, bf, acc0[1][jj], 0, 0, 0);
            }
        } else {
#pragma unroll
            for (int jj = 0; jj < 8; jj++) {
                short8 bf = *(const short8*)&bB[(128 * jc + 16 * jj + l15) * 32 + rq];
                acc1[0][jj] = __builtin_amdgcn_mfma_f32_16x16x32_bf16(af0, bf, acc1[0][jj], 0, 0, 0);
                acc1[1][jj] = __builtin_amdgcn_mfma_f32_16x16x32_bf16(af1, bf, acc1[1][jj], 0, 0, 0);
            }
        }
        __syncthreads();
    }

    // gate + store acts[b][t][o]
    u16* ab = acts + (size_t)b * T * 256;
#pragma unroll
    for (int m = 0; m < 2; m++)
#pragma unroll
        for (int jj = 0; jj < 8; jj++) {
            int o = 128 * jc + 16 * jj + l15;
#pragma unroll
            for (int r = 0; r < 4; r++) {
                int t = t0 + 32 * iw + 16 * m + quad * 4 + r;
                float at = acc0[m][jj][r], as = acc1[m][jj][r];
                float e2 = __expf(2.f * at);
                float th = 1.f - 2.f / (e2 + 1.f);
                float sg = 1.f / (1.f + __expf(-as));
                ab[(size_t)t * 256 + o] = f2b(th * sg);
            }
        }
}

// ================= layer rs kernel: 1x1 conv (K=256) + residual/skip update =================
// Same skeleton; 8 K-steps x 2 halves = 16 chunks. x updated IN PLACE (own tile only).
__global__ __launch_bounds__(512, 1) void layer_rs(
    const u16* __restrict__ acts, u16* __restrict__ x, const u16* __restrict__ Wrs,
    const u16* __restrict__ rsb, u16* __restrict__ oacc, int layer, int first, int last) {
    __shared__ u16 lds[28672];
    const int tid = threadIdx.x;
    const int w = tid >> 6, lane = tid & 63;
    const int l15 = lane & 15, quad = lane >> 4;
    const int iw = w >> 1, jc = w & 1;
    const int b = blockIdx.y, t0 = blockIdx.x * 128;
    const int lrow = lane >> 2;
    const int lsw = ((lane & 3) ^ (lrow & 3)) * 8;
    const int rq = (quad ^ (l15 & 3)) * 8;

    const u16* ab = acts + (size_t)b * T * 256;
    const u16* Wr = Wrs + (size_t)layer * 512 * 256;

    float4v acc0[2][8], acc1[2][8];
#pragma unroll
    for (int m = 0; m < 2; m++)
#pragma unroll
        for (int jj = 0; jj < 8; jj++) {
            acc0[m][jj] = (float4v){0.f, 0.f, 0.f, 0.f};
            acc1[m][jj] = (float4v){0.f, 0.f, 0.f, 0.f};
        }

    auto stageA = [&](int s, int abuf) {
        gl_lds16(ab + (size_t)(t0 + 16 * w + lrow) * 256 + s * 32 + lsw,
                 &lds[abuf * 4096 + w * 512]);
    };
    auto stageB = [&](int c) {
        int s = c >> 1;
        const u16* src = Wr + (size_t)((c & 1) * 256 + 32 * w + lrow) * 256 + s * 32 + lsw;
        u16* dst = &lds[12288 + (c & 1) * 8192 + w * 1024];
        gl_lds16(src, dst);
        gl_lds16(src + (size_t)16 * 256, dst + 512);
    };

    stageA(0, 0);
    stageA(1, 1);
    stageB(0);
    __syncthreads();
#pragma unroll 1
    for (int c = 0; c < 16; c++) {
        int s = c >> 1;
        if ((c & 1) == 0 && s + 2 < 8) stageA(s + 2, (s + 2) % 3);
        if (c + 1 < 16) stageB(c + 1);
        const u16* bA = &lds[(s % 3) * 4096];
        const u16* bB = &lds[12288 + (c & 1) * 8192];
        short8 af0 = *(const short8*)&bA[(32 * iw + l15) * 32 + rq];
        short8 af1 = *(const short8*)&bA[(32 * iw + 16 + l15) * 32 + rq];
        if ((c & 1) == 0) {
#pragma unroll
            for (int jj = 0; jj < 8; jj++) {
                short8 bf = *(const short8*)&bB[(128 * jc + 16 * jj + l15) * 32 + rq];
                acc0[0][jj] = __builtin_amdgcn_mfma_f32_16x16x32_bf16(af0, bf, acc0[0][jj], 0, 0, 0);
                acc0[1][jj] = __builtin_amdgcn_mfma_f32_16x16x32_bf16(af1, bf, acc0[1][jj], 0, 0, 0);
            }
        } else {
#pragma unroll
            for (int jj = 0; jj < 8; jj++) {
                short8 bf = *(const short8*)&bB[(128 * jc + 16 * jj + l15) * 32 + rq];
                acc1[0][jj] = __builtin_amdgcn_mfma_f32_16x16x32_bf16(af0, bf, acc1[0][jj], 0, 0, 0);
                acc1[1][jj] = __builtin_amdgcn_mfma_f32_16x16x32_bf16(af1, bf, acc1[1][jj], 0, 0, 0);
            }
        }
        __syncthreads();
    }

    u16* xv = x + (size_t)b * T * 256;
    u16* oo = oacc + (size_t)b * T * 256;
#pragma unroll
    for (int m = 0; m < 2; m++)
#pragma unroll
        for (int jj = 0; jj < 8; jj++) {
            int o = 128 * jc + 16 * jj + l15;
            float b0 = b2f(rsb[layer * 512 + o]);
            float b1 = b2f(rsb[layer * 512 + 256 + o]);
#pragma unroll
            for (int r = 0; r < 4; r++) {
                int t = t0 + 32 * iw + 16 * m + quad * 4 + r;
                size_t idx = (size_t)t * 256 + o;
                float v0 = acc0[m][jj][r] + b0;
                if (last) {
                    oo[idx] = f2b(b2f(oo[idx]) + v0);  // last: rs[:256] -> skip
                } else {
                    xv[idx] = f2b(b2f(xv[idx]) + v0);  // residual (in place, own tile)
                    float v1 = acc1[m][jj][r] + b1;
                    oo[idx] = first ? f2b(v1) : f2b(b2f(oo[idx]) + v1);
                }
            }
        }
}

// ---------------- end conv (256 -> 8) + affine + output assembly ----------------
template <bool F32>
__global__ void end_kernel(const u16* __restrict__ oacc, const void* __restrict__ w_end,
                           const void* __restrict__ b_end, const void* __restrict__ fc,
                           void* __restrict__ out, const int* __restrict__ flag) {
    if (skipv<F32>(flag)) return;
    __shared__ float wsm[2048];
    __shared__ float bsm[8];
    const int tid = threadIdx.x;
    for (int it = 0; it < 8; it++) wsm[it * 256 + tid] = LD<F32>(w_end, it * 256 + tid);
    if (tid < 8) bsm[tid] = LD<F32>(b_end, tid);
    __syncthreads();
    int gid = blockIdx.x * 256 + tid;  // 0..32767
    int b = gid >> 12, t = gid & 4095;
    float o8[8];
#pragma unroll
    for (int o = 0; o < 8; o++) o8[o] = bsm[o];
    const u16* orow = oacc + (size_t)(b * T + t) * 256;
    for (int c8 = 0; c8 < 32; c8++) {
        short8 v8 = *(const short8*)(orow + c8 * 8);
#pragma unroll
        for (int k = 0; k < 8; k++) {
            float v = b2f((u16)v8[k]);
            int c = c8 * 8 + k;
#pragma unroll
            for (int o = 0; o < 8; o++) o8[o] += wsm[o * 256 + c] * v;
        }
    }
    size_t ob8 = (size_t)b * 8 * T;
#pragma unroll
    for (int j = 0; j < 4; j++) {
        float f1v = LD<F32>(fc, ob8 + (size_t)(4 + j) * T + t);
        float ls = o8[4 + j];
        float val = __expf(ls) * f1v + o8[j];
        if constexpr (F32) {
            float* o = (float*)out;
            o[ob8 + (size_t)j * T + t] = ((const float*)fc)[ob8 + (size_t)j * T + t];
            o[ob8 + (size_t)(4 + j) * T + t] = val;
            o[(size_t)BATCH * 8 * T + ((size_t)b * 4 + j) * T + t] = ls;
        } else {
            u16* o = (u16*)out;
            o[ob8 + (size_t)j * T + t] = ((const u16*)fc)[ob8 + (size_t)j * T + t];
            o[ob8 + (size_t)(4 + j) * T + t] = f2b(val);
            o[(size_t)BATCH * 8 * T + ((size_t)b * 4 + j) * T + t] = f2b(ls);
        }
    }
}

template <bool F32>
static void launch_prep(const void* forecast, const void* context, const void* start_w,
                        const void* start_b, const void* cond_w, const void* cond_b,
                        const void* in_w, const void* in_b, const void* rs_w, const void* rs_b,
                        u16* xA, u16* ctxt, u16* Wc, u16* Wrs, u16* rsb, const int* flag,
                        hipStream_t stream) {
    cvt_kernel<F32><<<4096, 256, 0, stream>>>(rs_w, Wrs, 8 * 512 * 256, flag);
    cvt_kernel<F32><<<16, 256, 0, stream>>>(rs_b, rsb, 4096, flag);
    prep_wc<F32><<<4096, 256, 0, stream>>>(in_w, in_b, cond_w, cond_b, Wc, flag);
    prep_ctx<F32><<<dim3(64, BATCH), 256, 0, stream>>>(context, ctxt, flag);
    start_kernel<F32><<<dim3(64, BATCH), 256, 0, stream>>>(forecast, start_w, start_b, xA, flag);
}

extern "C" void kernel_launch(void* const* d_in, const int* in_sizes, int n_in,
                              void* d_out, int out_size, void* d_ws, size_t ws_size,
                              hipStream_t stream) {
    const void* forecast = d_in[0];
    const void* context  = d_in[1];
    const void* start_w  = d_in[2];
    const void* start_b  = d_in[3];
    const void* cond_w   = d_in[4];
    const void* cond_b   = d_in[5];
    const void* in_w     = d_in[6];
    const void* in_b     = d_in[7];
    const void* rs_w     = d_in[8];
    const void* rs_b     = d_in[9];
    const void* end_w    = d_in[10];
    const void* end_b    = d_in[11];

    char* W = (char*)d_ws;
    int* flag = (int*)(W + 0);
    u16* xA   = (u16*)(W + 256);                  // 16,777,216
    u16* oacc = (u16*)(W + 256 + 16777216);       // 16,777,216
    u16* acts = (u16*)(W + 256 + 33554432);       // 16,777,216
    u16* ctxt = (u16*)(W + 256 + 50331648);       //  6,291,456
    u16* Wc   = (u16*)(W + 256 + 56623104);       //  7,077,888
    u16* Wrs  = (u16*)(W + 256 + 63700992);       //  2,097,152
    u16* rsb  = (u16*)(W + 256 + 65798144);       //      8,192  -> total ~62.8 MiB

    probe_kernel<<<1, 256, 0, stream>>>((const u16*)forecast, flag);

    launch_prep<false>(forecast, context, start_w, start_b, cond_w, cond_b, in_w, in_b, rs_w,
                       rs_b, xA, ctxt, Wc, Wrs, rsb, flag, stream);
    launch_prep<true>(forecast, context, start_w, start_b, cond_w, cond_b, in_w, in_b, rs_w,
                      rs_b, xA, ctxt, Wc, Wrs, rsb, flag, stream);

    const int dil[NLAYERS] = {1, 2, 4, 8, 16, 32, 64, 128};
    for (int l = 0; l < NLAYERS; l++) {
        layer_conv<<<dim3(32, BATCH), 512, 0, stream>>>(xA, Wc, ctxt, acts, l, dil[l]);
        layer_rs<<<dim3(32, BATCH), 512, 0, stream>>>(acts, xA, Wrs, rsb, oacc, l,
                                                      l == 0, l == NLAYERS - 1);
    }

    end_kernel<false><<<128, 256, 0, stream>>>(oacc, end_w, end_b, forecast, d_out, flag);
    end_kernel<true><<<128, 256, 0, stream>>>(oacc, end_w, end_b, forecast, d_out, flag);
}